// Round 12
// baseline (3967.168 us; speedup 1.0000x reference)
//
#include <hip/hip_runtime.h>

typedef __attribute__((ext_vector_type(8))) short short8;
typedef __attribute__((ext_vector_type(4))) float f32x4;
typedef __attribute__((ext_vector_type(4))) float float4v;
typedef __attribute__((ext_vector_type(4))) unsigned short u16x4;
typedef __attribute__((ext_vector_type(4))) unsigned int u32x4;

#define T_TOT   1024
#define BATCH   64
#define HID     512
#define G4      2048
#define NGRID   128     // lstm blocks: 8 batch-groups x 16 hid-tiles
#define BH      (BATCH * HID)

static __device__ __forceinline__ unsigned short f2bf(float x) {
  union { float f; unsigned u; } v; v.f = x;
  unsigned r = v.u + 0x7FFFu + ((v.u >> 16) & 1u);
  return (unsigned short)(r >> 16);
}
static __device__ __forceinline__ float sigm(float x) {
  return 1.0f / (1.0f + __expf(-x));
}
static __device__ __forceinline__ float tanh_fast(float x) {
  return 1.0f - 2.0f / (__expf(2.0f * x) + 1.0f);
}
// LDS-only barrier: does NOT drain vmcnt (unlike __syncthreads).
static __device__ __forceinline__ void bar_lds() {
  asm volatile("s_waitcnt lgkmcnt(0)" ::: "memory");
  __builtin_amdgcn_s_barrier();
  asm volatile("" ::: "memory");
}

// ---------------------------------------------------------------- init
__global__ void init_k(const float* __restrict__ h0, const float* __restrict__ c0,
                       unsigned int* __restrict__ hb2, float* __restrict__ cst,
                       float* __restrict__ hst) {
  const int i = blockIdx.x * 256 + threadIdx.x;
  if (i < BH) {
    const float h = h0[i];
    hb2[i] = (unsigned)f2bf(h);               // tag 0 | h0
    hb2[BH + i] = 0xFFFF0000u;                // invalid tag
    hst[i] = h;
    cst[i] = c0[i];
  }
}

// ------------------------------------------------ gemm body (device fn)
// xz = x@W_ih^T + b, repacked per-consumer-block:
// xzp[((t*8+mb)*16+nb)*1024 + r*128 + g*32 + col]   (r<8 rows, g<4, col<32)
static __device__ __forceinline__ void gemm_body(
    int bm, int bn, const float* __restrict__ A, const float* __restrict__ W,
    const float* __restrict__ bih, const float* __restrict__ bhh,
    float* __restrict__ xzp) {
  __shared__ unsigned short As[128 * 64];
  __shared__ unsigned short Bs[128 * 64];
  const int tid  = threadIdx.x;
  const int lane = tid & 63;
  const int wid  = tid >> 6;
  const int wm   = (wid >> 1) * 64;
  const int wn   = (wid & 1) * 64;
  const int l15  = lane & 15;
  const int l4   = lane >> 4;

  f32x4 acc[4][4];
#pragma unroll
  for (int mt = 0; mt < 4; ++mt)
#pragma unroll
    for (int nt = 0; nt < 4; ++nt) acc[mt][nt] = f32x4{0.f, 0.f, 0.f, 0.f};

  const float* Ab = A + (long)bm * 128 * 512;
  const float* Wb = W + (long)bn * 128 * 512;
  const int r0 = tid >> 4;
  const int cq = (tid & 15) * 4;

  for (int k0 = 0; k0 < 512; k0 += 64) {
#pragma unroll
    for (int pass = 0; pass < 8; ++pass) {
      const int r = pass * 16 + r0;
      const float4v va = *(const float4v*)(Ab + (long)r * 512 + k0 + cq);
      const float4v vb = *(const float4v*)(Wb + (long)r * 512 + k0 + cq);
      u16x4 pa, pb;
#pragma unroll
      for (int j = 0; j < 4; ++j) { pa[j] = f2bf(va[j]); pb[j] = f2bf(vb[j]); }
      const int boff = r * 128 + ((cq * 2) ^ ((r & 7) << 4));
      *(u16x4*)((char*)As + boff) = pa;
      *(u16x4*)((char*)Bs + boff) = pb;
    }
    __syncthreads();
#pragma unroll
    for (int kk = 0; kk < 2; ++kk) {
      short8 af[4], bfv[4];
#pragma unroll
      for (int mt = 0; mt < 4; ++mt) {
        const int row = wm + mt * 16 + l15;
        af[mt] = *(const short8*)((const char*)As + row * 128 +
                                  ((kk * 64 + l4 * 16) ^ ((row & 7) << 4)));
      }
#pragma unroll
      for (int nt = 0; nt < 4; ++nt) {
        const int row = wn + nt * 16 + l15;
        bfv[nt] = *(const short8*)((const char*)Bs + row * 128 +
                                   ((kk * 64 + l4 * 16) ^ ((row & 7) << 4)));
      }
#pragma unroll
      for (int mt = 0; mt < 4; ++mt)
#pragma unroll
        for (int nt = 0; nt < 4; ++nt)
          acc[mt][nt] = __builtin_amdgcn_mfma_f32_16x16x32_bf16(af[mt], bfv[nt], acc[mt][nt], 0, 0, 0);
    }
    __syncthreads();
  }

#pragma unroll
  for (int nt = 0; nt < 4; ++nt) {
    const int gn = bn * 128 + wn + nt * 16 + l15;
    const float bias = bih[gn] + bhh[gn];
    const int g2   = gn >> 9;
    const int hh   = gn & 511;
    const int nb2  = hh >> 5;
    const int col2 = hh & 31;
#pragma unroll
    for (int mt = 0; mt < 4; ++mt) {
      const int m0 = bm * 128 + wm + mt * 16 + l4 * 4;
#pragma unroll
      for (int r = 0; r < 4; ++r) {
        const int m = m0 + r;
        const int tt2 = m >> 6, brow = m & 63;
        const int mb2 = brow >> 3, r2 = brow & 7;
        xzp[((((size_t)tt2 * 8 + mb2) * 16 + nb2) << 10) + r2 * 128 + g2 * 32 + col2] =
            acc[mt][nt][r] + bias;
      }
    }
  }
}

__global__ __launch_bounds__(256) void xz_gemm(
    const float* __restrict__ A, const float* __restrict__ W,
    const float* __restrict__ bih, const float* __restrict__ bhh,
    float* __restrict__ xzp) {
  gemm_body(blockIdx.x, blockIdx.y, A, W, bih, bhh, xzp);
}

// -------------------------------------------------------- fused chunk
// Blocks 0..127: lstm (R10 uniform protocol + two R12 refinements):
//   1) stores-last tail FIFO [X(8), D(4), exch(2), ys(1)] with entry
//      s_waitcnt vmcnt(3): completes X+D, never waits store acks.
//   2) own-patch h' is written directly into h_lds (2B/thread) during the
//      tail; validation+staging skip own-block granules (tt>0) — a block
//      never round-trips its own data through global memory.
// Exchange words self-validating (tag|bf16); sc0 probe (local L2, seeded by
// the plain second store), escalating to sc0sc1 (MALL) after 3 tries.
__global__ __launch_bounds__(256, 1) void fused_chunk(
    const float* __restrict__ xnext,
    const float* __restrict__ Wih,
    const float* __restrict__ bih, const float* __restrict__ bhh,
    float* __restrict__ xzp_next,
    const float* __restrict__ xzp_cur,
    const float* __restrict__ Whh,     // [2048][512]
    const float* __restrict__ alpha_p,
    float* __restrict__ out,           // d_out
    unsigned int* __restrict__ hb2,    // 2 x [64][512] tagged u32
    float* __restrict__ cst, float* __restrict__ hst,
    int t0, int Tc) {
  const int bx = blockIdx.x;
  if (bx >= NGRID) {
    const int g = bx - NGRID;
    gemm_body(g >> 4, g & 15, xnext, Wih, bih, bhh, xzp_next);
    return;
  }

  const int mb  = bx & 7;          // batch group (8 rows) == target XCD
  const int nb  = bx >> 3;         // hid tile (32 cols), 0..15
  const int rb0 = mb * 8;
  const int hs0 = nb * 32;
  const int tid = threadIdx.x;
  const int lane = tid & 63;
  const int w   = tid >> 6;        // wave = gate index
  const int l15 = lane & 15;
  const int l4  = lane >> 4;

  __shared__ __align__(16) unsigned short h_lds[16 * HID];   // 16 KB
  __shared__ __align__(16) float gates[4][16][36];

  // Weights: gate w, hid cols hs0..hs0+31 (two 16-col tiles), K=512.
  short8 wf0[16], wf1[16];
  {
    const float* wr0 = Whh + (long)(w * HID + hs0 + l15) * HID + l4 * 8;
    const float* wr1 = Whh + (long)(w * HID + hs0 + 16 + l15) * HID + l4 * 8;
#pragma unroll
    for (int ks = 0; ks < 16; ++ks) {
      float4v lo = *(const float4v*)(wr0 + ks * 32);
      float4v hi = *(const float4v*)(wr0 + ks * 32 + 4);
      short8 f;
#pragma unroll
      for (int j = 0; j < 4; ++j) { f[j] = (short)f2bf(lo[j]); f[j+4] = (short)f2bf(hi[j]); }
      wf0[ks] = f;
      lo = *(const float4v*)(wr1 + ks * 32);
      hi = *(const float4v*)(wr1 + ks * 32 + 4);
#pragma unroll
      for (int j = 0; j < 4; ++j) { f[j] = (short)f2bf(lo[j]); f[j+4] = (short)f2bf(hi[j]); }
      wf1[ks] = f;
    }
  }
  const float a = alpha_p[0];
  const float oma = 1.0f - a;

  // Zero LDS rows 8..15 once (MFMA pads M=8 -> 16 with zero rows).
  for (int idx = tid; idx < 512; idx += 256) {
    const int r = 8 + (idx >> 6), c = idx & 63;
    *(u32x4*)((char*)h_lds + c * 256 + ((r ^ (c & 15)) << 4)) = u32x4{0u,0u,0u,0u};
  }

  const int em = tid >> 5;          // state row 0..7
  const int en = tid & 31;          // state col 0..31 (== sweep span index)
  float cp = cst[(long)(rb0 + em) * HID + hs0 + en];
  float hp = hst[(long)(rb0 + em) * HID + hs0 + en];
  bar_lds();

  const long YS = (long)T_TOT * BATCH * HID;
  const int swr = tid >> 5;         // sweep row 0..7
  const int swc = (tid & 31) * 16;  // sweep col base
  const bool ownlane = ((en >> 1) == nb);   // this lane's sweep span == own cols
  // own-patch LDS address (this thread's h' element)
  const int c3 = nb * 4 + (en >> 3);
  char* ownp = (char*)h_lds + c3 * 256 + ((em ^ (c3 & 15)) << 4) + (en & 7) * 2;

  // prologue: X(t0) then D(t0)  (issue order defines the vmcnt FIFO)
  float xzv[8];
  u32x4 sv[4];
  {
    const float* xb = xzp_cur + ((((size_t)0 * 8 + mb) * 16 + nb) << 10);
#pragma unroll
    for (int n = 0; n < 2; ++n)
#pragma unroll
      for (int j = 0; j < 4; ++j) {
        const float* p = xb + ((l4 * 4 + j) & 7) * 128 + w * 32 + n * 16 + l15;
        asm volatile("global_load_dword %0, %1, off" : "=v"(xzv[n*4+j]) : "v"(p));
      }
    const unsigned int* p0 = hb2 + (size_t)(t0 & 1) * BH +
                             (size_t)(rb0 + swr) * HID + swc;
#pragma unroll
    for (int i = 0; i < 4; ++i)
      asm volatile("global_load_dwordx4 %0, %1, off sc0" : "=v"(sv[i]) : "v"(p0 + i * 4));
  }

  for (int tt = 0; tt < Tc; ++tt) {
    const int t = t0 + tt;

    // Entry wait. Steady-state FIFO from tail(t-1): [X(8), D(4), exch(2),
    // ys(1)] (+3 aged store acks) -> vmcnt(3) completes X+D, leaves the 3
    // newest store acks in flight. tt==0: full drain of prologue.
    if (tt == 0) asm volatile("s_waitcnt vmcnt(0)" ::: "memory");
    else         asm volatile("s_waitcnt vmcnt(3)" ::: "memory");
    __builtin_amdgcn_sched_barrier(0);

    // Tag validation; own-block spans skipped for tt>0 (h' arrives via the
    // direct LDS write). Retry: 3x sc0 (local L2) then sc0sc1 (MALL).
    {
      const unsigned wantHi = ((unsigned)t) << 16;
      const bool own = (tt > 0) && ownlane;
      const unsigned int* p0 = hb2 + (size_t)(t & 1) * BH +
                               (size_t)(rb0 + swr) * HID + swc;
      int tries = 0;
      for (;;) {
        unsigned bad = 0u;
        if (!own) {
#pragma unroll
          for (int i = 0; i < 4; ++i) {
            unsigned d = (sv[i][0] ^ wantHi) | (sv[i][1] ^ wantHi) |
                         (sv[i][2] ^ wantHi) | (sv[i][3] ^ wantHi);
            if (d & 0xFFFF0000u) bad |= (1u << i);
          }
        }
        if (!__any(bad != 0u)) break;
        if (tries < 3) {
#pragma unroll
          for (int i = 0; i < 4; ++i)
            if (bad & (1u << i))
              asm volatile("global_load_dwordx4 %0, %1, off sc0"
                           : "=v"(sv[i]) : "v"(p0 + i * 4));
        } else {
#pragma unroll
          for (int i = 0; i < 4; ++i)
            if (bad & (1u << i))
              asm volatile("global_load_dwordx4 %0, %1, off sc0 sc1"
                           : "=v"(sv[i]) : "v"(p0 + i * 4));
        }
        ++tries;
        asm volatile("s_waitcnt vmcnt(0)" ::: "memory");
        __builtin_amdgcn_sched_barrier(0);
      }

      // Stage non-own spans -> 2 x 16B LDS chunks (r = swr, c = en*2 + q).
      if (!own) {
#pragma unroll
        for (int q = 0; q < 2; ++q) {
          u32x4 pk;
          pk[0] = __builtin_amdgcn_perm(sv[q*2][1],   sv[q*2][0],   0x05040100u);
          pk[1] = __builtin_amdgcn_perm(sv[q*2][3],   sv[q*2][2],   0x05040100u);
          pk[2] = __builtin_amdgcn_perm(sv[q*2+1][1], sv[q*2+1][0], 0x05040100u);
          pk[3] = __builtin_amdgcn_perm(sv[q*2+1][3], sv[q*2+1][2], 0x05040100u);
          const int c = en * 2 + q;
          *(u32x4*)((char*)h_lds + c * 256 + ((swr ^ (c & 15)) << 4)) = pk;
        }
      }
    }
    bar_lds();   // bar A: h_lds(t) complete

    // gates[8x32] for gate w = h[8x512] @ W^T : 2 N-tiles x 2 chains each.
    f32x4 ac00, ac01, ac10, ac11;
    ac00 = f32x4{xzv[0], xzv[1], xzv[2], xzv[3]};
    ac10 = f32x4{xzv[4], xzv[5], xzv[6], xzv[7]};
    ac01 = f32x4{0.f, 0.f, 0.f, 0.f};
    ac11 = ac01;
#pragma unroll
    for (int ks = 0; ks < 16; ks += 2) {
      const int c0 = ks * 4 + l4;
      const int c1 = c0 + 4;
      const short8 af0 = *(const short8*)((const char*)h_lds + c0 * 256 +
                                          ((l15 ^ (c0 & 15)) << 4));
      const short8 af1 = *(const short8*)((const char*)h_lds + c1 * 256 +
                                          ((l15 ^ (c1 & 15)) << 4));
      ac00 = __builtin_amdgcn_mfma_f32_16x16x32_bf16(af0, wf0[ks],   ac00, 0, 0, 0);
      ac10 = __builtin_amdgcn_mfma_f32_16x16x32_bf16(af0, wf1[ks],   ac10, 0, 0, 0);
      ac01 = __builtin_amdgcn_mfma_f32_16x16x32_bf16(af1, wf0[ks+1], ac01, 0, 0, 0);
      ac11 = __builtin_amdgcn_mfma_f32_16x16x32_bf16(af1, wf1[ks+1], ac11, 0, 0, 0);
    }
    {
      const f32x4 s0 = ac00 + ac01;
      const f32x4 s1 = ac10 + ac11;
#pragma unroll
      for (int r = 0; r < 4; ++r) {
        gates[w][l4 * 4 + r][l15]      = s0[r];
        gates[w][l4 * 4 + r][16 + l15] = s1[r];
      }
    }
    bar_lds();   // bar B: gates complete

    // ---- tail: X loads FIRST (oldest), stores LAST (newest) ----
    if (tt < Tc - 1) {
      const float* xb = xzp_cur + ((((size_t)(tt + 1) * 8 + mb) * 16 + nb) << 10);
#pragma unroll
      for (int n = 0; n < 2; ++n)
#pragma unroll
        for (int j = 0; j < 4; ++j) {
          const float* p = xb + ((l4 * 4 + j) & 7) * 128 + w * 32 + n * 16 + l15;
          asm volatile("global_load_dword %0, %1, off" : "=v"(xzv[n*4+j]) : "v"(p));
        }
    }

    // Elementwise: one element per thread; state in registers.
    const float gi = gates[0][em][en], gf = gates[1][em][en];
    const float gg = gates[2][em][en], go = gates[3][em][en];
    const float ii = sigm(gi), ff = sigm(gf), oo = sigm(go);
    const float g  = tanh_fast(gg);
    const float cn = ff * cp + ii * g;
    const float hn = oo * tanh_fast(cn);
    const float co = a * cn + oma * cp;
    const float ho = a * hn + oma * hp;
    cp = co;
    hp = ho;
    const unsigned hob = (unsigned)f2bf(ho);

    // Own-patch direct LDS write for the next step (2B, disjoint from staging).
    *(unsigned short*)ownp = (unsigned short)hob;

    // D probes for t+1 (before the stores in the FIFO).
    if (tt < Tc - 1) {
      const unsigned int* pn = hb2 + (size_t)((t + 1) & 1) * BH +
                               (size_t)(rb0 + swr) * HID + swc;
#pragma unroll
      for (int i = 0; i < 4; ++i)
        asm volatile("global_load_dwordx4 %0, %1, off sc0" : "=v"(sv[i]) : "v"(pn + i * 4));
    }

    // Exchange: MALL publish (sc0sc1) + local-L2 seed (plain). Newest in FIFO.
    {
      unsigned int* dst = hb2 + (size_t)((t + 1) & 1) * BH +
                          (long)(rb0 + em) * HID + hs0 + en;
      const unsigned w32 = (((unsigned)(t + 1)) << 16) | hob;
      asm volatile("global_store_dword %0, %1, off sc0 sc1"
                   :: "v"((const void*)dst), "v"(w32) : "memory");
      asm volatile("global_store_dword %0, %1, off"
                   :: "v"((const void*)dst), "v"(w32) : "memory");
    }
    if (tt < Tc - 1) {
      const float* op = out + ((long)t * BATCH + rb0 + em) * HID + hs0 + en;
      asm volatile("global_store_dword %0, %1, off"
                   :: "v"((const void*)op), "v"(ho) : "memory");
    }
  }

  // epilogue
  {
    const int tl = t0 + Tc - 1;
    out[((long)tl * BATCH + rb0 + em) * HID + hs0 + en] = hp;
    if (t0 + Tc == T_TOT) {
      out[YS + (long)(rb0 + em) * HID + hs0 + en] = hp;
      out[YS + BATCH * HID + (long)(rb0 + em) * HID + hs0 + en] = cp;
    }
    cst[(long)(rb0 + em) * HID + hs0 + en] = cp;
    hst[(long)(rb0 + em) * HID + hs0 + en] = hp;
  }
}

// ---------------------------------------------------------------- host
extern "C" void kernel_launch(void* const* d_in, const int* in_sizes, int n_in,
                              void* d_out, int out_size, void* d_ws, size_t ws_size,
                              hipStream_t stream) {
  const float* x     = (const float*)d_in[0];
  const float* h0    = (const float*)d_in[1];
  const float* c0    = (const float*)d_in[2];
  const float* W_ih  = (const float*)d_in[3];
  const float* W_hh  = (const float*)d_in[4];
  const float* b_ih  = (const float*)d_in[5];
  const float* b_hh  = (const float*)d_in[6];
  const float* alpha = (const float*)d_in[7];
  float* out = (float*)d_out;

  int Tc = 128;
  while ((size_t)2 * (size_t)Tc * 524288ull + 786432ull > ws_size && Tc > 2) Tc >>= 1;

  char* ws = (char*)d_ws;
  unsigned int* hb2 = (unsigned int*)(ws + 0);              // 256 KB tagged h
  float* cst = (float*)(ws + 262144);                       // 128 KB
  float* hst = (float*)(ws + 393216);                       // 128 KB
  float* xzp0 = (float*)(ws + 786432);
  float* xzp1 = (float*)(ws + 786432 + (size_t)Tc * 524288ull);
  float* xzp[2] = {xzp0, xzp1};

  const int nchunk = T_TOT / Tc;
  const size_t xoff = (size_t)Tc * BATCH * 512;
  const int nG = (Tc / 2) * 16;

  init_k<<<128, 256, 0, stream>>>(h0, c0, hb2, cst, hst);
  {
    dim3 gg(Tc / 2, 16);
    xz_gemm<<<gg, 256, 0, stream>>>(x, W_ih, b_ih, b_hh, xzp[0]);
  }
  for (int k = 0; k < nchunk; ++k) {
    const bool last = (k == nchunk - 1);
    const int grid = NGRID + (last ? 0 : nG);
    fused_chunk<<<grid, 256, 0, stream>>>(
        x + (size_t)(k + 1) * xoff, W_ih, b_ih, b_hh, xzp[(k + 1) & 1],
        xzp[k & 1], W_hh, alpha, out, hb2, cst, hst, k * Tc, Tc);
  }
}

// Round 14
// 2443.719 us; speedup vs baseline: 1.6234x; 1.6234x over previous
//
#include <hip/hip_runtime.h>

typedef __attribute__((ext_vector_type(8))) short short8;
typedef __attribute__((ext_vector_type(4))) float f32x4;
typedef __attribute__((ext_vector_type(4))) float float4v;
typedef __attribute__((ext_vector_type(4))) unsigned short u16x4;
typedef __attribute__((ext_vector_type(4))) unsigned int u32x4;

#define T_TOT   1024
#define BATCH   64
#define HID     512
#define G4      2048
#define NGRID   128     // lstm blocks: 8 batch-groups x 16 hid-tiles
#define BH      (BATCH * HID)

static __device__ __forceinline__ unsigned short f2bf(float x) {
  union { float f; unsigned u; } v; v.f = x;
  unsigned r = v.u + 0x7FFFu + ((v.u >> 16) & 1u);
  return (unsigned short)(r >> 16);
}
static __device__ __forceinline__ float sigm(float x) {
  return 1.0f / (1.0f + __expf(-x));
}
static __device__ __forceinline__ float tanh_fast(float x) {
  return 1.0f - 2.0f / (__expf(2.0f * x) + 1.0f);
}
// LDS-only barrier: does NOT drain vmcnt (unlike __syncthreads).
static __device__ __forceinline__ void bar_lds() {
  asm volatile("s_waitcnt lgkmcnt(0)" ::: "memory");
  __builtin_amdgcn_s_barrier();
  asm volatile("" ::: "memory");
}

// ---------------------------------------------------------------- init
__global__ void init_k(const float* __restrict__ h0, const float* __restrict__ c0,
                       unsigned int* __restrict__ hb2, float* __restrict__ cst,
                       float* __restrict__ hst) {
  const int i = blockIdx.x * 256 + threadIdx.x;
  if (i < BH) {
    const float h = h0[i];
    hb2[i] = (unsigned)f2bf(h);               // tag 0 | h0
    hb2[BH + i] = 0xFFFF0000u;                // invalid tag
    hst[i] = h;
    cst[i] = c0[i];
  }
}

// ------------------------------------------------ gemm body (device fn)
// xz = x@W_ih^T + b, repacked per-consumer-block:
// xzp[((t*8+mb)*16+nb)*1024 + r*128 + g*32 + col]   (r<8 rows, g<4, col<32)
static __device__ __forceinline__ void gemm_body(
    int bm, int bn, const float* __restrict__ A, const float* __restrict__ W,
    const float* __restrict__ bih, const float* __restrict__ bhh,
    float* __restrict__ xzp) {
  __shared__ unsigned short As[128 * 64];
  __shared__ unsigned short Bs[128 * 64];
  const int tid  = threadIdx.x;
  const int lane = tid & 63;
  const int wid  = tid >> 6;
  const int wm   = (wid >> 1) * 64;
  const int wn   = (wid & 1) * 64;
  const int l15  = lane & 15;
  const int l4   = lane >> 4;

  f32x4 acc[4][4];
#pragma unroll
  for (int mt = 0; mt < 4; ++mt)
#pragma unroll
    for (int nt = 0; nt < 4; ++nt) acc[mt][nt] = f32x4{0.f, 0.f, 0.f, 0.f};

  const float* Ab = A + (long)bm * 128 * 512;
  const float* Wb = W + (long)bn * 128 * 512;
  const int r0 = tid >> 4;
  const int cq = (tid & 15) * 4;

  for (int k0 = 0; k0 < 512; k0 += 64) {
#pragma unroll
    for (int pass = 0; pass < 8; ++pass) {
      const int r = pass * 16 + r0;
      const float4v va = *(const float4v*)(Ab + (long)r * 512 + k0 + cq);
      const float4v vb = *(const float4v*)(Wb + (long)r * 512 + k0 + cq);
      u16x4 pa, pb;
#pragma unroll
      for (int j = 0; j < 4; ++j) { pa[j] = f2bf(va[j]); pb[j] = f2bf(vb[j]); }
      const int boff = r * 128 + ((cq * 2) ^ ((r & 7) << 4));
      *(u16x4*)((char*)As + boff) = pa;
      *(u16x4*)((char*)Bs + boff) = pb;
    }
    __syncthreads();
#pragma unroll
    for (int kk = 0; kk < 2; ++kk) {
      short8 af[4], bfv[4];
#pragma unroll
      for (int mt = 0; mt < 4; ++mt) {
        const int row = wm + mt * 16 + l15;
        af[mt] = *(const short8*)((const char*)As + row * 128 +
                                  ((kk * 64 + l4 * 16) ^ ((row & 7) << 4)));
      }
#pragma unroll
      for (int nt = 0; nt < 4; ++nt) {
        const int row = wn + nt * 16 + l15;
        bfv[nt] = *(const short8*)((const char*)Bs + row * 128 +
                                   ((kk * 64 + l4 * 16) ^ ((row & 7) << 4)));
      }
#pragma unroll
      for (int mt = 0; mt < 4; ++mt)
#pragma unroll
        for (int nt = 0; nt < 4; ++nt)
          acc[mt][nt] = __builtin_amdgcn_mfma_f32_16x16x32_bf16(af[mt], bfv[nt], acc[mt][nt], 0, 0, 0);
    }
    __syncthreads();
  }

#pragma unroll
  for (int nt = 0; nt < 4; ++nt) {
    const int gn = bn * 128 + wn + nt * 16 + l15;
    const float bias = bih[gn] + bhh[gn];
    const int g2   = gn >> 9;
    const int hh   = gn & 511;
    const int nb2  = hh >> 5;
    const int col2 = hh & 31;
#pragma unroll
    for (int mt = 0; mt < 4; ++mt) {
      const int m0 = bm * 128 + wm + mt * 16 + l4 * 4;
#pragma unroll
      for (int r = 0; r < 4; ++r) {
        const int m = m0 + r;
        const int tt2 = m >> 6, brow = m & 63;
        const int mb2 = brow >> 3, r2 = brow & 7;
        xzp[((((size_t)tt2 * 8 + mb2) * 16 + nb2) << 10) + r2 * 128 + g2 * 32 + col2] =
            acc[mt][nt][r] + bias;
      }
    }
  }
}

__global__ __launch_bounds__(256) void xz_gemm(
    const float* __restrict__ A, const float* __restrict__ W,
    const float* __restrict__ bih, const float* __restrict__ bhh,
    float* __restrict__ xzp) {
  gemm_body(blockIdx.x, blockIdx.y, A, W, bih, bhh, xzp);
}

// -------------------------------------------------------- fused chunk
// Blocks 0..127: lstm. mb = bx&7 -> under round-robin dispatch all 16 blocks
// of group mb share one XCD/L2. Producer publishes each tagged word twice:
// sc0sc1 (MALL, cross-XCD correctness) then plain (local-L2 seed). Consumer
// probes with sc0 (own-L2, hits the dirty seed when co-located); tag mismatch
// falls back to sc0sc1 MALL reads. Correct under any block->XCD mapping.
__global__ __launch_bounds__(256, 1) void fused_chunk(
    const float* __restrict__ xnext,   // x slice of chunk k+1
    const float* __restrict__ Wih,
    const float* __restrict__ bih, const float* __restrict__ bhh,
    float* __restrict__ xzp_next,
    const float* __restrict__ xzp_cur,
    const float* __restrict__ Whh,     // [2048][512]
    const float* __restrict__ alpha_p,
    float* __restrict__ out,           // d_out
    unsigned int* __restrict__ hb2,    // 2 x [64][512] tagged u32
    float* __restrict__ cst, float* __restrict__ hst,
    int t0, int Tc) {
  const int bx = blockIdx.x;
  if (bx >= NGRID) {
    const int g = bx - NGRID;
    gemm_body(g >> 4, g & 15, xnext, Wih, bih, bhh, xzp_next);
    return;
  }

  const int mb  = bx & 7;          // batch group (8 rows) == target XCD
  const int nb  = bx >> 3;         // hid tile (32 cols), 0..15
  const int rb0 = mb * 8;
  const int hs0 = nb * 32;
  const int tid = threadIdx.x;
  const int lane = tid & 63;
  const int w   = tid >> 6;        // wave = gate index
  const int l15 = lane & 15;
  const int l4  = lane >> 4;

  // h rows as 16B chunks: addr = c*256 + ((r ^ (c&15))<<4); rows 8..15 zero.
  __shared__ __align__(16) unsigned short h_lds[16 * HID];   // 16 KB
  __shared__ __align__(16) float gates[4][16][36];

  // Weights: gate w, hid cols hs0..hs0+31 (two 16-col tiles), K=512.
  short8 wf0[16], wf1[16];
  {
    const float* wr0 = Whh + (long)(w * HID + hs0 + l15) * HID + l4 * 8;
    const float* wr1 = Whh + (long)(w * HID + hs0 + 16 + l15) * HID + l4 * 8;
#pragma unroll
    for (int ks = 0; ks < 16; ++ks) {
      float4v lo = *(const float4v*)(wr0 + ks * 32);
      float4v hi = *(const float4v*)(wr0 + ks * 32 + 4);
      short8 f;
#pragma unroll
      for (int j = 0; j < 4; ++j) { f[j] = (short)f2bf(lo[j]); f[j+4] = (short)f2bf(hi[j]); }
      wf0[ks] = f;
      lo = *(const float4v*)(wr1 + ks * 32);
      hi = *(const float4v*)(wr1 + ks * 32 + 4);
#pragma unroll
      for (int j = 0; j < 4; ++j) { f[j] = (short)f2bf(lo[j]); f[j+4] = (short)f2bf(hi[j]); }
      wf1[ks] = f;
    }
  }
  const float a = alpha_p[0];
  const float oma = 1.0f - a;

  // Zero LDS rows 8..15 once (MFMA pads M=8 -> 16 with zero rows).
  for (int idx = tid; idx < 512; idx += 256) {
    const int r = 8 + (idx >> 6), c = idx & 63;
    *(u32x4*)((char*)h_lds + c * 256 + ((r ^ (c & 15)) << 4)) = u32x4{0u,0u,0u,0u};
  }

  const int em = tid >> 5;          // state row 0..7
  const int en = tid & 31;          // state col 0..31
  float cp = cst[(long)(rb0 + em) * HID + hs0 + en];
  float hp = hst[(long)(rb0 + em) * HID + hs0 + en];
  bar_lds();

  const long YS = (long)T_TOT * BATCH * HID;
  const int swr = tid >> 5;         // sweep row 0..7
  const int swc = (tid & 31) * 16;  // sweep col base

  // prologue: X(t0) then D(t0)  (issue order defines the vmcnt FIFO)
  float xzv[8];
  u32x4 sv[4];
  {
    const float* xb = xzp_cur + ((((size_t)0 * 8 + mb) * 16 + nb) << 10);
#pragma unroll
    for (int n = 0; n < 2; ++n)
#pragma unroll
      for (int j = 0; j < 4; ++j) {
        const float* p = xb + ((l4 * 4 + j) & 7) * 128 + w * 32 + n * 16 + l15;
        asm volatile("global_load_dword %0, %1, off" : "=v"(xzv[n*4+j]) : "v"(p));
      }
    const unsigned int* p0 = hb2 + (size_t)(t0 & 1) * BH +
                             (size_t)(rb0 + swr) * HID + swc;
#pragma unroll
    for (int i = 0; i < 4; ++i)
      asm volatile("global_load_dwordx4 %0, %1, off sc0" : "=v"(sv[i]) : "v"(p0 + i * 4));
  }

  for (int tt = 0; tt < Tc; ++tt) {
    const int t = t0 + tt;

    // Entry wait: steady-state FIFO [exch(2), X(8), D(4), ys(1)] -> vmcnt(1)
    // completes exch+X+D (in-order retirement), leaves the ys ack in flight.
    if (tt == 0) asm volatile("s_waitcnt vmcnt(0)" ::: "memory");
    else         asm volatile("s_waitcnt vmcnt(1)" ::: "memory");
    __builtin_amdgcn_sched_barrier(0);

    // Tag validation; stale granules retry via MALL (sc0 sc1).
    {
      const unsigned wantHi = ((unsigned)t) << 16;
      const unsigned int* p0 = hb2 + (size_t)(t & 1) * BH +
                               (size_t)(rb0 + swr) * HID + swc;
      for (;;) {
        unsigned bad = 0u;
#pragma unroll
        for (int i = 0; i < 4; ++i) {
          unsigned d = 0u;
#pragma unroll
          for (int j = 0; j < 4; ++j) d |= (sv[i][j] ^ wantHi);
          if (d & 0xFFFF0000u) bad |= (1u << i);
        }
        if (!__any(bad != 0u)) break;
#pragma unroll
        for (int i = 0; i < 4; ++i)
          if (bad & (1u << i))
            asm volatile("global_load_dwordx4 %0, %1, off sc0 sc1"
                         : "=v"(sv[i]) : "v"(p0 + i * 4));
        asm volatile("s_waitcnt vmcnt(0)" ::: "memory");
        __builtin_amdgcn_sched_barrier(0);
      }
    }

    // Pack lo16s -> 2 x 16B LDS chunks (r = swr, c = (tid&31)*2 + q).
#pragma unroll
    for (int q = 0; q < 2; ++q) {
      u32x4 pk;
      pk[0] = __builtin_amdgcn_perm(sv[q*2][1],   sv[q*2][0],   0x05040100u);
      pk[1] = __builtin_amdgcn_perm(sv[q*2][3],   sv[q*2][2],   0x05040100u);
      pk[2] = __builtin_amdgcn_perm(sv[q*2+1][1], sv[q*2+1][0], 0x05040100u);
      pk[3] = __builtin_amdgcn_perm(sv[q*2+1][3], sv[q*2+1][2], 0x05040100u);
      const int c = (tid & 31) * 2 + q;
      *(u32x4*)((char*)h_lds + c * 256 + ((swr ^ (c & 15)) << 4)) = pk;
    }
    bar_lds();

    // gates[8x32] for gate w = h[8x512] @ W^T : 2 N-tiles x 2 chains each.
    f32x4 ac00, ac01, ac10, ac11;
    ac00 = f32x4{xzv[0], xzv[1], xzv[2], xzv[3]};
    ac10 = f32x4{xzv[4], xzv[5], xzv[6], xzv[7]};
    ac01 = f32x4{0.f, 0.f, 0.f, 0.f};
    ac11 = ac01;
#pragma unroll
    for (int ks = 0; ks < 16; ks += 2) {
      const int c0 = ks * 4 + l4;
      const int c1 = c0 + 4;
      const short8 af0 = *(const short8*)((const char*)h_lds + c0 * 256 +
                                          ((l15 ^ (c0 & 15)) << 4));
      const short8 af1 = *(const short8*)((const char*)h_lds + c1 * 256 +
                                          ((l15 ^ (c1 & 15)) << 4));
      ac00 = __builtin_amdgcn_mfma_f32_16x16x32_bf16(af0, wf0[ks],   ac00, 0, 0, 0);
      ac10 = __builtin_amdgcn_mfma_f32_16x16x32_bf16(af0, wf1[ks],   ac10, 0, 0, 0);
      ac01 = __builtin_amdgcn_mfma_f32_16x16x32_bf16(af1, wf0[ks+1], ac01, 0, 0, 0);
      ac11 = __builtin_amdgcn_mfma_f32_16x16x32_bf16(af1, wf1[ks+1], ac11, 0, 0, 0);
    }
    {
      const f32x4 s0 = ac00 + ac01;
      const f32x4 s1 = ac10 + ac11;
#pragma unroll
      for (int r = 0; r < 4; ++r) {
        gates[w][l4 * 4 + r][l15]      = s0[r];   // rows 8..15 unused pad
        gates[w][l4 * 4 + r][16 + l15] = s1[r];
      }
    }
    bar_lds();

    // Elementwise: one element per thread; state in registers.
    const float gi = gates[0][em][en], gf = gates[1][em][en];
    const float gg = gates[2][em][en], go = gates[3][em][en];
    const float ii = sigm(gi), ff = sigm(gf), oo = sigm(go);
    const float g  = tanh_fast(gg);
    const float cn = ff * cp + ii * g;
    const float hn = oo * tanh_fast(cn);
    const float co = a * cn + oma * cp;
    const float ho = a * hn + oma * hp;
    cp = co;
    hp = ho;

    // Double exchange store: MALL publish (sc0sc1) then local-L2 seed (plain).
    {
      unsigned int* dst = hb2 + (size_t)((t + 1) & 1) * BH +
                          (long)(rb0 + em) * HID + hs0 + en;
      const unsigned w32 = (((unsigned)(t + 1)) << 16) | (unsigned)f2bf(ho);
      asm volatile("global_store_dword %0, %1, off sc0 sc1"
                   :: "v"((const void*)dst), "v"(w32) : "memory");
      asm volatile("global_store_dword %0, %1, off"
                   :: "v"((const void*)dst), "v"(w32) : "memory");
    }

    if (tt < Tc - 1) {
      // X loads for tt+1 (8 dwords).
      const float* xb = xzp_cur + ((((size_t)(tt + 1) * 8 + mb) * 16 + nb) << 10);
#pragma unroll
      for (int n = 0; n < 2; ++n)
#pragma unroll
        for (int j = 0; j < 4; ++j) {
          const float* p = xb + ((l4 * 4 + j) & 7) * 128 + w * 32 + n * 16 + l15;
          asm volatile("global_load_dword %0, %1, off" : "=v"(xzv[n*4+j]) : "v"(p));
        }
      // D probes for t+1 (4 dwordx4, own-L2 fast path).
      const unsigned int* pn = hb2 + (size_t)((t + 1) & 1) * BH +
                               (size_t)(rb0 + swr) * HID + swc;
#pragma unroll
      for (int i = 0; i < 4; ++i)
        asm volatile("global_load_dwordx4 %0, %1, off sc0" : "=v"(sv[i]) : "v"(pn + i * 4));
      // Deferred ys store of step t (newest in FIFO; ack never waited).
      const float* op = out + ((long)t * BATCH + rb0 + em) * HID + hs0 + en;
      asm volatile("global_store_dword %0, %1, off"
                   :: "v"((const void*)op), "v"(ho) : "memory");
    }
  }

  // epilogue
  {
    const int tl = t0 + Tc - 1;
    out[((long)tl * BATCH + rb0 + em) * HID + hs0 + en] = hp;
    if (t0 + Tc == T_TOT) {
      out[YS + (long)(rb0 + em) * HID + hs0 + en] = hp;
      out[YS + BATCH * HID + (long)(rb0 + em) * HID + hs0 + en] = cp;
    }
    cst[(long)(rb0 + em) * HID + hs0 + en] = cp;
    hst[(long)(rb0 + em) * HID + hs0 + en] = hp;
  }
}

// ---------------------------------------------------------------- host
extern "C" void kernel_launch(void* const* d_in, const int* in_sizes, int n_in,
                              void* d_out, int out_size, void* d_ws, size_t ws_size,
                              hipStream_t stream) {
  const float* x     = (const float*)d_in[0];
  const float* h0    = (const float*)d_in[1];
  const float* c0    = (const float*)d_in[2];
  const float* W_ih  = (const float*)d_in[3];
  const float* W_hh  = (const float*)d_in[4];
  const float* b_ih  = (const float*)d_in[5];
  const float* b_hh  = (const float*)d_in[6];
  const float* alpha = (const float*)d_in[7];
  float* out = (float*)d_out;

  int Tc = 128;
  while ((size_t)2 * (size_t)Tc * 524288ull + 786432ull > ws_size && Tc > 2) Tc >>= 1;

  char* ws = (char*)d_ws;
  unsigned int* hb2 = (unsigned int*)(ws + 0);              // 256 KB tagged h
  float* cst = (float*)(ws + 262144);                       // 128 KB
  float* hst = (float*)(ws + 393216);                       // 128 KB
  float* xzp0 = (float*)(ws + 786432);
  float* xzp1 = (float*)(ws + 786432 + (size_t)Tc * 524288ull);
  float* xzp[2] = {xzp0, xzp1};

  const int nchunk = T_TOT / Tc;
  const size_t xoff = (size_t)Tc * BATCH * 512;
  const int nG = (Tc / 2) * 16;

  init_k<<<128, 256, 0, stream>>>(h0, c0, hb2, cst, hst);
  {
    dim3 gg(Tc / 2, 16);
    xz_gemm<<<gg, 256, 0, stream>>>(x, W_ih, b_ih, b_hh, xzp[0]);
  }
  for (int k = 0; k < nchunk; ++k) {
    const bool last = (k == nchunk - 1);
    const int grid = NGRID + (last ? 0 : nG);
    fused_chunk<<<grid, 256, 0, stream>>>(
        x + (size_t)(k + 1) * xoff, W_ih, b_ih, b_hh, xzp[(k + 1) & 1],
        xzp[k & 1], W_hh, alpha, out, hb2, cst, hst, k * Tc, Tc);
  }
}